// Round 13
// baseline (290.583 us; speedup 1.0000x reference)
//
#include <hip/hip_runtime.h>
#include <cfloat>

// BruteForce top-K: B=512 x N=500000, D=128 fp32, K=100.
// (1) bf16 MFMA scoring, persistent-ish blocks: 512 blocks (2/CU) x 4 waves;
//     each wave holds a 128-query slice as B-fragments in REGISTERS (loaded
//     ONCE); candidate tiles (128 x 128, bf16, XOR-swizzled) stream through
//     a double-buffered 2x32KB LDS with load-early/write-late staging so HBM
//     hides under MFMA. Fused filter t_q = 3.25*|q| (~289 survivors/query).
// (2) fallback (only if cnt<K or cnt>cap): exact fp32 rescan, top-min(cap,256).
// (3) select: numpy-bit-exact fp32 re-score of survivors, rank by
//     (value desc, id asc). Exact output.

#define D_DIM 128
#define K_TOP 100
#define THRESH_SIGMA 3.25f
#define CAP_MAX 512
#define KEEP_MAXF 256
#define FGRID 512

typedef short bf16x8 __attribute__((ext_vector_type(8)));
typedef float f32x4 __attribute__((ext_vector_type(4)));

__device__ __forceinline__ unsigned short f2bf(float x) {  // RNE fp32->bf16
    unsigned u = __float_as_uint(x);
    return (unsigned short)((u + 0x7FFFu + ((u >> 16) & 1u)) >> 16);
}

__device__ __forceinline__ unsigned long long make_key(float v, unsigned id) {
    unsigned vb = __float_as_uint(v);
    unsigned vm = (vb & 0x80000000u) ? ~vb : (vb | 0x80000000u);  // monotone map
    return ((unsigned long long)vm << 32) | (0xFFFFFFFFu - id);   // val asc; id asc on tie
}

template <int S>
__device__ inline void bitonic_sort_u64(unsigned long long* buf) {
    for (int k = 2; k <= S; k <<= 1) {
        for (int j = k >> 1; j > 0; j >>= 1) {
            __syncthreads();
            for (int i = threadIdx.x; i < S; i += blockDim.x) {
                int l = i ^ j;
                if (l > i) {
                    unsigned long long a = buf[i], b = buf[l];
                    bool sw = ((i & k) == 0) ? (a > b) : (a < b);
                    if (sw) { buf[i] = b; buf[l] = a; }
                }
            }
        }
    }
    __syncthreads();
}

// threshold + counter zero
__global__ void prep2_kernel(const float* __restrict__ Qm, float* __restrict__ thr,
                             int* __restrict__ cnt, int B) {
    int b = blockIdx.x * blockDim.x + threadIdx.x;
    if (b >= B) return;
    float s = 0.f;
    for (int d = 0; d < D_DIM; ++d) { float v = Qm[(size_t)b * D_DIM + d]; s = fmaf(v, v, s); }
    thr[b] = THRESH_SIGMA * sqrtf(s);
    cnt[b] = 0;
}

// build query B-fragments in MFMA order: qf[((qch*8+qb)*4+ks)*64 + l] =
// 8 bf16 of Q[qch*128+qb*16+(l&15)][ks*32+(l>>4)*8 .. +8]
__global__ void qfrag_kernel(const float* __restrict__ Qm, uint4* __restrict__ qf,
                             int B, int nch) {
    int tid = blockIdx.x * blockDim.x + threadIdx.x;
    int total = nch * 8 * 4 * 64;
    if (tid >= total) return;
    int l  = tid & 63;
    int ks = (tid >> 6) & 3;
    int qb = (tid >> 8) & 7;
    int qch = tid >> 11;
    int qrow = qch * 128 + qb * 16 + (l & 15);
    int k0 = ks * 32 + (l >> 4) * 8;
    uint4 o = make_uint4(0u, 0u, 0u, 0u);
    if (qrow < B) {
        const float* src = Qm + (size_t)qrow * D_DIM + k0;
        unsigned r[4];
#pragma unroll
        for (int j = 0; j < 4; ++j)
            r[j] = (unsigned)f2bf(src[2 * j]) | ((unsigned)f2bf(src[2 * j + 1]) << 16);
        o = make_uint4(r[0], r[1], r[2], r[3]);
    }
    qf[tid] = o;
}

// bf16 MFMA + filter, double-buffered candidate streaming.
__global__ __launch_bounds__(256, 2) void mfma_filter_kernel(
    const float* __restrict__ cand, const bf16x8* __restrict__ qfrag,
    const float* __restrict__ thr, unsigned* __restrict__ idbuf,
    int* __restrict__ cnt, int N, int Bg, int cap, int nch, int ntiles) {
    __shared__ char cl[2][32768];
    const int t = threadIdx.x;
    const int w = t >> 6;            // wave 0..3
    const int l = t & 63;

    // ---- per-wave query chunk: B-fragments + thresholds, loaded ONCE ----
    const bool qvalid = (w < nch);
    const int qch = qvalid ? w : (nch - 1);
    bf16x8 bq[8][4];
#pragma unroll
    for (int qb = 0; qb < 8; ++qb)
#pragma unroll
        for (int ks = 0; ks < 4; ++ks)
            bq[qb][ks] = qfrag[((qch * 8 + qb) * 4 + ks) * 64 + l];
    float tvq[8];
#pragma unroll
    for (int qb = 0; qb < 8; ++qb) {
        int qg = qch * 128 + qb * 16 + (l & 15);
        tvq[qb] = (qvalid && qg < Bg) ? thr[qg] : 3.0e38f;
    }

    // ---- staging helpers (8 float4/thread per half = 64 cand rows) ----
    float4 ra[8];
    auto stage_load = [&](int tile, int h) {
        int c0t = tile * 128;
#pragma unroll
        for (int i = 0; i < 8; ++i) {
            int f4 = (h * 8 + i) * 256 + t;
            int row = f4 >> 5;
            int colf4 = f4 & 31;
            int gc = c0t + row;
            float4 v = make_float4(0.f, 0.f, 0.f, 0.f);
            if (gc < N) v = *reinterpret_cast<const float4*>(cand + (size_t)gc * D_DIM + colf4 * 4);
            ra[i] = v;
        }
    };
    auto stage_write = [&](int buf, int h) {
#pragma unroll
        for (int i = 0; i < 8; ++i) {
            int f4 = (h * 8 + i) * 256 + t;
            int row = f4 >> 5;
            int colf4 = f4 & 31;
            uint2 pk;
            pk.x = (unsigned)f2bf(ra[i].x) | ((unsigned)f2bf(ra[i].y) << 16);
            pk.y = (unsigned)f2bf(ra[i].z) | ((unsigned)f2bf(ra[i].w) << 16);
            int byte = row * 256 + ((colf4 * 8) ^ ((row & 7) << 4));
            *reinterpret_cast<uint2*>(cl[buf] + byte) = pk;
        }
    };
    auto compute_half = [&](int buf, int h, int c0) {
#pragma unroll
        for (int cbi = 0; cbi < 4; ++cbi) {
            int cb = h * 4 + cbi;
            int row = cb * 16 + (l & 15);
            int sw = (row & 7) << 4;
            bf16x8 af[4];
#pragma unroll
            for (int ks = 0; ks < 4; ++ks) {
                int byte = row * 256 + ((ks * 64 + ((l >> 4) * 16)) ^ sw);
                af[ks] = *reinterpret_cast<const bf16x8*>(cl[buf] + byte);
            }
            f32x4 acc[8];
#pragma unroll
            for (int qb = 0; qb < 8; ++qb) acc[qb] = (f32x4){0.f, 0.f, 0.f, 0.f};
#pragma unroll
            for (int ks = 0; ks < 4; ++ks) {
                bf16x8 a = af[ks];
#pragma unroll
                for (int qb = 0; qb < 8; ++qb)
                    acc[qb] = __builtin_amdgcn_mfma_f32_16x16x32_bf16(
                        a, bq[qb][ks], acc[qb], 0, 0, 0);
            }
            // epilogue: D col=lane&15 (query), row=(lane>>4)*4+reg (cand)
#pragma unroll
            for (int qb = 0; qb < 8; ++qb) {
                float tv = tvq[qb];
                f32x4 a = acc[qb];
                float m = fmaxf(fmaxf(a[0], a[1]), fmaxf(a[2], a[3]));
                if (m > tv) {
                    int qg = qch * 128 + qb * 16 + (l & 15);
#pragma unroll
                    for (int r = 0; r < 4; ++r) {
                        if (a[r] > tv) {
                            int cid = c0 + cb * 16 + ((l >> 4) << 2) + r;
                            if (cid < N) {
                                int pos = atomicAdd(&cnt[qg], 1);
                                if (pos < cap) idbuf[(size_t)qg * cap + pos] = (unsigned)cid;
                            }
                        }
                    }
                }
            }
        }
    };

    // ---- prologue: stage first tile into buf 0 ----
    int tile = blockIdx.x;
    if (tile >= ntiles) return;
    stage_load(tile, 0); stage_write(0, 0);
    stage_load(tile, 1); stage_write(0, 1);
    __syncthreads();

    int cur = 0;
#pragma unroll 1
    while (true) {
        int nxt = tile + FGRID;
        bool have_next = (nxt < ntiles);
        int c0 = tile * 128;

        if (have_next) stage_load(nxt, 0);     // issue early (hide under MFMA)
        compute_half(cur, 0, c0);
        if (have_next) stage_write(cur ^ 1, 0);
        if (have_next) stage_load(nxt, 1);
        compute_half(cur, 1, c0);
        if (have_next) stage_write(cur ^ 1, 1);

        if (!have_next) break;
        __syncthreads();
        cur ^= 1; tile = nxt;
    }
}

// exact fallback: keeps top-keep (keep = min(cap,256)) by fp32
__global__ void fallback_kernel(const float* __restrict__ Qm, const float* __restrict__ cand,
                                unsigned* __restrict__ idbuf, int* __restrict__ cnt,
                                int N, int cap) {
    int q = blockIdx.x;
    int c0 = cnt[q];
    if (c0 >= K_TOP && c0 <= cap) return;
    int keep = (cap < KEEP_MAXF) ? cap : KEEP_MAXF;

    __shared__ unsigned long long buf[2048];
    __shared__ float qrow[D_DIM];
    __shared__ int bn;
    __shared__ float theta;
    __shared__ int validn;
    for (int i = threadIdx.x; i < D_DIM; i += blockDim.x) qrow[i] = Qm[(size_t)q * D_DIM + i];
    for (int i = threadIdx.x; i < 2048; i += blockDim.x) buf[i] = 0ULL;
    if (threadIdx.x == 0) { bn = 0; theta = -3.0e38f; }
    __syncthreads();

    for (int base = 0; base < N; base += blockDim.x) {
        int c = base + threadIdx.x;
        if (c < N) {
            float s = 0.f;
            for (int d = 0; d < D_DIM; ++d) s = fmaf(qrow[d], cand[(size_t)c * D_DIM + d], s);
            if (s > theta) {
                int p = atomicAdd(&bn, 1);
                if (p < 2048) buf[p] = make_key(s, (unsigned)c);
            }
        }
        __syncthreads();
        if (bn > 2048 - 256 - 8) {  // compress: keep top-keep, raise theta
            bitonic_sort_u64<2048>(buf);
            unsigned long long kv = (threadIdx.x < (unsigned)keep) ? buf[2047 - threadIdx.x] : 0ULL;
            __syncthreads();
            for (int i = threadIdx.x; i < 2048; i += blockDim.x) buf[i] = 0ULL;
            __syncthreads();
            if (threadIdx.x < (unsigned)keep) buf[threadIdx.x] = kv;
            if ((int)threadIdx.x == keep - 1) {
                unsigned vm = (unsigned)(kv >> 32);
                unsigned vb = (vm & 0x80000000u) ? (vm ^ 0x80000000u) : ~vm;
                theta = __uint_as_float(vb) - 0.01f;
            }
            if (threadIdx.x == 0) bn = keep;
            __syncthreads();
        }
    }
    bitonic_sort_u64<2048>(buf);
    if (threadIdx.x == 0) validn = 0;
    __syncthreads();
    unsigned long long kv = (threadIdx.x < (unsigned)keep) ? buf[2047 - threadIdx.x] : 0ULL;
    if (kv != 0ULL) atomicAdd(&validn, 1);
    __syncthreads();
    if ((int)threadIdx.x < validn && threadIdx.x < (unsigned)keep) {
        unsigned id = 0xFFFFFFFFu - (unsigned)(kv & 0xFFFFFFFFu);
        if (id < (unsigned)N) idbuf[(size_t)q * cap + threadIdx.x] = id;
    }
    if (threadIdx.x == 0) cnt[q] = (validn < keep) ? validn : keep;
}

// --- bit-exact emulation of numpy einsum fp32 dot (SSE baseline, no FMA) ---
__device__ __forceinline__ float np_lane_chain(float q0, float b0v, float q1, float b1v,
                                               float q2, float b2v, float q3, float b3v,
                                               float acc) {
    float t = __fadd_rn(__fmul_rn(q3, b3v), acc);
    t = __fadd_rn(__fmul_rn(q2, b2v), t);
    t = __fadd_rn(__fmul_rn(q1, b1v), t);
    return __fadd_rn(__fmul_rn(q0, b0v), t);
}

__device__ __forceinline__ float np_score(const float* __restrict__ qrow,
                                          const float* __restrict__ crow) {
    float acc0 = 0.f, acc1 = 0.f, acc2 = 0.f, acc3 = 0.f;
#pragma unroll
    for (int d0 = 0; d0 < D_DIM; d0 += 16) {
        float4 b0 = *reinterpret_cast<const float4*>(crow + d0 + 0);
        float4 b1 = *reinterpret_cast<const float4*>(crow + d0 + 4);
        float4 b2 = *reinterpret_cast<const float4*>(crow + d0 + 8);
        float4 b3 = *reinterpret_cast<const float4*>(crow + d0 + 12);
        acc0 = np_lane_chain(qrow[d0 + 0], b0.x, qrow[d0 + 4], b1.x,
                             qrow[d0 + 8], b2.x, qrow[d0 + 12], b3.x, acc0);
        acc1 = np_lane_chain(qrow[d0 + 1], b0.y, qrow[d0 + 5], b1.y,
                             qrow[d0 + 9], b2.y, qrow[d0 + 13], b3.y, acc1);
        acc2 = np_lane_chain(qrow[d0 + 2], b0.z, qrow[d0 + 6], b1.z,
                             qrow[d0 + 10], b2.z, qrow[d0 + 14], b3.z, acc2);
        acc3 = np_lane_chain(qrow[d0 + 3], b0.w, qrow[d0 + 7], b1.w,
                             qrow[d0 + 11], b2.w, qrow[d0 + 15], b3.w, acc3);
    }
    return __fadd_rn(__fadd_rn(acc0, acc1), __fadd_rn(acc2, acc3));
}

// selection: numpy-exact fp32 re-score, rank by (value desc, id asc)
__global__ __launch_bounds__(256) void select_kernel(
    const float* __restrict__ Qm, const float* __restrict__ cand,
    const unsigned* __restrict__ idbuf, const int* __restrict__ cnt,
    const int* __restrict__ ident, float* __restrict__ out, int N, int B, int cap) {
    __shared__ unsigned long long skey[CAP_MAX];
    __shared__ float qrow[D_DIM];
    int q = blockIdx.x;
    for (int i = threadIdx.x; i < D_DIM; i += blockDim.x) qrow[i] = Qm[(size_t)q * D_DIM + i];
    __syncthreads();

    int n = cnt[q]; if (n > cap) n = cap; if (n > CAP_MAX) n = CAP_MAX;
    for (int i = threadIdx.x; i < CAP_MAX; i += blockDim.x) {
        unsigned long long key = 0ULL;
        if (i < n) {
            unsigned id = idbuf[(size_t)q * cap + i];
            if (id < (unsigned)N) {
                float s = np_score(qrow, cand + (size_t)id * D_DIM);
                key = make_key(s, id);
            }
        }
        skey[i] = key;
    }

    bitonic_sort_u64<CAP_MAX>(skey);   // ascending: best at the end

    for (int t = threadIdx.x; t < K_TOP; t += blockDim.x) {
        unsigned long long key = skey[CAP_MAX - 1 - t];
        unsigned vm = (unsigned)(key >> 32);
        unsigned vb = (vm & 0x80000000u) ? (vm ^ 0x80000000u) : ~vm;
        unsigned id = 0xFFFFFFFFu - (unsigned)(key & 0xFFFFFFFFu);
        if (id >= (unsigned)N) id = 0;  // unreachable pad guard
        out[(size_t)q * K_TOP + t] = __uint_as_float(vb);
        out[(size_t)B * K_TOP + (size_t)q * K_TOP + t] = (float)ident[id];
    }
}

extern "C" void kernel_launch(void* const* d_in, const int* in_sizes, int n_in,
                              void* d_out, int out_size, void* d_ws, size_t ws_size,
                              hipStream_t stream) {
    const float* queries = (const float*)d_in[0];
    const float* cands   = (const float*)d_in[1];
    const int*   ident   = (const int*)d_in[2];
    const int B = in_sizes[0] / D_DIM;   // 512
    const int N = in_sizes[2];           // 500000
    float* out = (float*)d_out;
    const int nch = (B + 127) >> 7;
    const int ntiles = (N + 127) / 128;

    // ws layout: cnt (2KB) | thr (2KB) | qfrag (nch*32KB) | idbuf
    char* ws = (char*)d_ws;
    int*   cnt = (int*)ws;
    float* thr = (float*)(ws + 2048);
    uint4* qfrag = (uint4*)(ws + 4096);
    size_t ids_off = 4096 + (size_t)nch * 32768;
    unsigned* idbuf = (unsigned*)(ws + ids_off);
    int cap = CAP_MAX;
    if (ws_size > ids_off) {
        size_t fit = (ws_size - ids_off) / ((size_t)B * 4);
        if (fit < (size_t)cap) cap = (int)fit;
    } else cap = 1;
    if (cap < 1) cap = 1;

    prep2_kernel<<<(B + 255) / 256, 256, 0, stream>>>(queries, thr, cnt, B);
    int qft = nch * 2048;
    qfrag_kernel<<<(qft + 255) / 256, 256, 0, stream>>>(queries, qfrag, B, nch);

    // filter per 512-query group (one group for B=512)
    int ngrp = (nch + 3) / 4;
    for (int g = 0; g < ngrp; ++g) {
        int nch_g = nch - g * 4; if (nch_g > 4) nch_g = 4;
        int B_g = B - g * 512; if (B_g > 512) B_g = 512;
        mfma_filter_kernel<<<FGRID, 256, 0, stream>>>(
            cands, (const bf16x8*)(qfrag + (size_t)g * 8192),
            thr + (size_t)g * 512, idbuf + (size_t)g * 512 * cap,
            cnt + (size_t)g * 512, N, B_g, cap, nch_g, ntiles);
    }

    fallback_kernel<<<B, 256, 0, stream>>>(queries, cands, idbuf, cnt, N, cap);

    select_kernel<<<B, 256, 0, stream>>>(queries, cands, idbuf, cnt, ident, out, N, B, cap);
}

// Round 14
// 165.628 us; speedup vs baseline: 1.7544x; 1.7544x over previous
//
#include <hip/hip_runtime.h>
#include <cfloat>

// BruteForce top-K: B=512 x N=500000, D=128 fp32, K=100.
// (1) bf16 MFMA scoring, streaming: 512 blocks x 4 waves; each wave holds its
//     128-query slice as B-fragments in REGISTERS (loaded once). Candidate
//     tiles (64 rows x 128 fp32 = 32 KB) stream through a double-buffered
//     LDS via __builtin_amdgcn_global_load_lds (zero-VGPR async DMA), with
//     pre-swizzled per-lane global source (unit ^= row&7) so fragment
//     ds_read_b128s are 2-way-conflict-free. Counted s_waitcnt vmcnt(8) +
//     raw s_barrier (never vmcnt(0) mid-loop) keeps the prefetch in flight.
//     fp32->bf16 by truncating pack at fragment load (error << margin).
//     Fused filter t_q = 3.25*|q| (~289 survivors/query).
// (2) fallback (only if cnt<K or cnt>cap): exact fp32 rescan, top-min(cap,256).
// (3) select: numpy-bit-exact fp32 re-score of survivors, rank by
//     (value desc, id asc). Exact output.

#define D_DIM 128
#define K_TOP 100
#define THRESH_SIGMA 3.25f
#define CAP_MAX 512
#define KEEP_MAXF 256
#define FGRID 512
#define TROWS 64

typedef short bf16x8 __attribute__((ext_vector_type(8)));
typedef float f32x4 __attribute__((ext_vector_type(4)));

__device__ __forceinline__ unsigned short f2bf(float x) {  // RNE fp32->bf16
    unsigned u = __float_as_uint(x);
    return (unsigned short)((u + 0x7FFFu + ((u >> 16) & 1u)) >> 16);
}

__device__ __forceinline__ unsigned long long make_key(float v, unsigned id) {
    unsigned vb = __float_as_uint(v);
    unsigned vm = (vb & 0x80000000u) ? ~vb : (vb | 0x80000000u);  // monotone map
    return ((unsigned long long)vm << 32) | (0xFFFFFFFFu - id);   // val asc; id asc on tie
}

template <int S>
__device__ inline void bitonic_sort_u64(unsigned long long* buf) {
    for (int k = 2; k <= S; k <<= 1) {
        for (int j = k >> 1; j > 0; j >>= 1) {
            __syncthreads();
            for (int i = threadIdx.x; i < S; i += blockDim.x) {
                int l = i ^ j;
                if (l > i) {
                    unsigned long long a = buf[i], b = buf[l];
                    bool sw = ((i & k) == 0) ? (a > b) : (a < b);
                    if (sw) { buf[i] = b; buf[l] = a; }
                }
            }
        }
    }
    __syncthreads();
}

// threshold + counter zero
__global__ void prep2_kernel(const float* __restrict__ Qm, float* __restrict__ thr,
                             int* __restrict__ cnt, int B) {
    int b = blockIdx.x * blockDim.x + threadIdx.x;
    if (b >= B) return;
    float s = 0.f;
    for (int d = 0; d < D_DIM; ++d) { float v = Qm[(size_t)b * D_DIM + d]; s = fmaf(v, v, s); }
    thr[b] = THRESH_SIGMA * sqrtf(s);
    cnt[b] = 0;
}

// build query B-fragments in MFMA order: qf[((qch*8+qb)*4+ks)*64 + l] =
// 8 bf16 of Q[qch*128+qb*16+(l&15)][ks*32+(l>>4)*8 .. +8]
__global__ void qfrag_kernel(const float* __restrict__ Qm, uint4* __restrict__ qf,
                             int B, int nch) {
    int tid = blockIdx.x * blockDim.x + threadIdx.x;
    int total = nch * 8 * 4 * 64;
    if (tid >= total) return;
    int l  = tid & 63;
    int ks = (tid >> 6) & 3;
    int qb = (tid >> 8) & 7;
    int qch = tid >> 11;
    int qrow = qch * 128 + qb * 16 + (l & 15);
    int k0 = ks * 32 + (l >> 4) * 8;
    uint4 o = make_uint4(0u, 0u, 0u, 0u);
    if (qrow < B) {
        const float* src = Qm + (size_t)qrow * D_DIM + k0;
        unsigned r[4];
#pragma unroll
        for (int j = 0; j < 4; ++j)
            r[j] = (unsigned)f2bf(src[2 * j]) | ((unsigned)f2bf(src[2 * j + 1]) << 16);
        o = make_uint4(r[0], r[1], r[2], r[3]);
    }
    qf[tid] = o;
}

// bf16 MFMA + filter, gload_lds double-buffered candidate streaming.
__global__ __launch_bounds__(256, 2) void mfma_filter_kernel(
    const float* __restrict__ cand, const bf16x8* __restrict__ qfrag,
    const float* __restrict__ thr, unsigned* __restrict__ idbuf,
    int* __restrict__ cnt, int N, int Bg, int cap, int nch, int ntiles) {
    __shared__ __align__(16) char cl[2][TROWS * 512];   // 2 x 32 KB fp32 tiles
    const int t = threadIdx.x;
    const int w = t >> 6;            // wave 0..3
    const int l = t & 63;

    // per-wave query chunk: B-fragments + thresholds, loaded ONCE
    const bool qv = (w < nch);
    const int qch = qv ? w : (nch > 0 ? nch - 1 : 0);
    bf16x8 bq[8][4];
#pragma unroll
    for (int qb = 0; qb < 8; ++qb)
#pragma unroll
        for (int ks = 0; ks < 4; ++ks)
            bq[qb][ks] = qfrag[((qch * 8 + qb) * 4 + ks) * 64 + l];
    float tvq[8];
#pragma unroll
    for (int qb = 0; qb < 8; ++qb) {
        int qg = qch * 128 + qb * 16 + (l & 15);
        tvq[qb] = (qv && qg < Bg) ? thr[qg] : 3.0e38f;
    }

    int tile = blockIdx.x;
    if (tile >= ntiles) return;

    // async stage: 8 gload_lds/wave; LDS dest linear (wave base + lane*16);
    // global source pre-swizzled: unit ^= (row&7)
#define STAGE(BUFI, T)                                                              \
    do {                                                                            \
        int c0s = (T) * TROWS;                                                      \
        _Pragma("unroll")                                                           \
        for (int i = 0; i < 8; ++i) {                                               \
            int rl = (w * 8 + i) * 2 + (l >> 5);                                    \
            int gr = c0s + rl; if (gr > N - 1) gr = N - 1;                          \
            int ug = (l & 31) ^ (rl & 7);                                           \
            const float* srcp = cand + (size_t)gr * D_DIM + ug * 4;                 \
            __builtin_amdgcn_global_load_lds(                                       \
                (const __attribute__((address_space(1))) void*)srcp,                \
                (__attribute__((address_space(3))) void*)(&cl[BUFI][(w * 8 + i) * 1024]), \
                16, 0, 0);                                                          \
        }                                                                           \
    } while (0)

    STAGE(0, tile);
    int cur = 0;
#pragma unroll 1
    while (true) {
        int nxt = tile + FGRID;
        bool hn = (nxt < ntiles);
        if (hn) {
            STAGE(cur ^ 1, nxt);
            asm volatile("s_waitcnt vmcnt(8)" ::: "memory");
        } else {
            asm volatile("s_waitcnt vmcnt(0)" ::: "memory");
        }
        __builtin_amdgcn_s_barrier();

        {   // compute cl[cur]
            const char* bp = cl[cur];
            int c0 = tile * TROWS;
#pragma unroll
            for (int cb = 0; cb < 4; ++cb) {
                int r = cb * 16 + (l & 15);
                int sb = r * 512, s = r & 7;
                bf16x8 af[4];
#pragma unroll
                for (int ks = 0; ks < 4; ++ks) {
                    int u0 = ks * 8 + (l >> 4) * 2;
                    f32x4 f0 = *reinterpret_cast<const f32x4*>(bp + sb + ((u0 ^ s) << 4));
                    f32x4 f1 = *reinterpret_cast<const f32x4*>(bp + sb + (((u0 + 1) ^ s) << 4));
                    union { bf16x8 v; unsigned u[4]; } p;
                    p.u[0] = (__float_as_uint(f0[0]) >> 16) | (__float_as_uint(f0[1]) & 0xFFFF0000u);
                    p.u[1] = (__float_as_uint(f0[2]) >> 16) | (__float_as_uint(f0[3]) & 0xFFFF0000u);
                    p.u[2] = (__float_as_uint(f1[0]) >> 16) | (__float_as_uint(f1[1]) & 0xFFFF0000u);
                    p.u[3] = (__float_as_uint(f1[2]) >> 16) | (__float_as_uint(f1[3]) & 0xFFFF0000u);
                    af[ks] = p.v;
                }
                f32x4 acc[8];
#pragma unroll
                for (int qb = 0; qb < 8; ++qb) acc[qb] = (f32x4){0.f, 0.f, 0.f, 0.f};
#pragma unroll
                for (int ks = 0; ks < 4; ++ks) {
                    bf16x8 a = af[ks];
#pragma unroll
                    for (int qb = 0; qb < 8; ++qb)
                        acc[qb] = __builtin_amdgcn_mfma_f32_16x16x32_bf16(
                            a, bq[qb][ks], acc[qb], 0, 0, 0);
                }
                // epilogue: D col=lane&15 (query), row=(lane>>4)*4+reg (cand)
#pragma unroll
                for (int qb = 0; qb < 8; ++qb) {
                    float tv = tvq[qb];
                    f32x4 a = acc[qb];
                    float m = fmaxf(fmaxf(a[0], a[1]), fmaxf(a[2], a[3]));
                    if (m > tv) {
                        int qg = qch * 128 + qb * 16 + (l & 15);
#pragma unroll
                        for (int rr = 0; rr < 4; ++rr) {
                            if (a[rr] > tv) {
                                int cid = c0 + cb * 16 + ((l >> 4) << 2) + rr;
                                if (cid < N) {
                                    int pos = atomicAdd(&cnt[qg], 1);
                                    if (pos < cap) idbuf[(size_t)qg * cap + pos] = (unsigned)cid;
                                }
                            }
                        }
                    }
                }
            }
        }

        if (!hn) break;
        __builtin_amdgcn_s_barrier();
        cur ^= 1; tile = nxt;
    }
#undef STAGE
}

// exact fallback: keeps top-keep (keep = min(cap,256)) by fp32
__global__ void fallback_kernel(const float* __restrict__ Qm, const float* __restrict__ cand,
                                unsigned* __restrict__ idbuf, int* __restrict__ cnt,
                                int N, int cap) {
    int q = blockIdx.x;
    int c0 = cnt[q];
    if (c0 >= K_TOP && c0 <= cap) return;
    int keep = (cap < KEEP_MAXF) ? cap : KEEP_MAXF;

    __shared__ unsigned long long buf[2048];
    __shared__ float qrow[D_DIM];
    __shared__ int bn;
    __shared__ float theta;
    __shared__ int validn;
    for (int i = threadIdx.x; i < D_DIM; i += blockDim.x) qrow[i] = Qm[(size_t)q * D_DIM + i];
    for (int i = threadIdx.x; i < 2048; i += blockDim.x) buf[i] = 0ULL;
    if (threadIdx.x == 0) { bn = 0; theta = -3.0e38f; }
    __syncthreads();

    for (int base = 0; base < N; base += blockDim.x) {
        int c = base + threadIdx.x;
        if (c < N) {
            float s = 0.f;
            for (int d = 0; d < D_DIM; ++d) s = fmaf(qrow[d], cand[(size_t)c * D_DIM + d], s);
            if (s > theta) {
                int p = atomicAdd(&bn, 1);
                if (p < 2048) buf[p] = make_key(s, (unsigned)c);
            }
        }
        __syncthreads();
        if (bn > 2048 - 256 - 8) {  // compress: keep top-keep, raise theta
            bitonic_sort_u64<2048>(buf);
            unsigned long long kv = (threadIdx.x < (unsigned)keep) ? buf[2047 - threadIdx.x] : 0ULL;
            __syncthreads();
            for (int i = threadIdx.x; i < 2048; i += blockDim.x) buf[i] = 0ULL;
            __syncthreads();
            if (threadIdx.x < (unsigned)keep) buf[threadIdx.x] = kv;
            if ((int)threadIdx.x == keep - 1) {
                unsigned vm = (unsigned)(kv >> 32);
                unsigned vb = (vm & 0x80000000u) ? (vm ^ 0x80000000u) : ~vm;
                theta = __uint_as_float(vb) - 0.01f;
            }
            if (threadIdx.x == 0) bn = keep;
            __syncthreads();
        }
    }
    bitonic_sort_u64<2048>(buf);
    if (threadIdx.x == 0) validn = 0;
    __syncthreads();
    unsigned long long kv = (threadIdx.x < (unsigned)keep) ? buf[2047 - threadIdx.x] : 0ULL;
    if (kv != 0ULL) atomicAdd(&validn, 1);
    __syncthreads();
    if ((int)threadIdx.x < validn && threadIdx.x < (unsigned)keep) {
        unsigned id = 0xFFFFFFFFu - (unsigned)(kv & 0xFFFFFFFFu);
        if (id < (unsigned)N) idbuf[(size_t)q * cap + threadIdx.x] = id;
    }
    if (threadIdx.x == 0) cnt[q] = (validn < keep) ? validn : keep;
}

// --- bit-exact emulation of numpy einsum fp32 dot (SSE baseline, no FMA) ---
__device__ __forceinline__ float np_lane_chain(float q0, float b0v, float q1, float b1v,
                                               float q2, float b2v, float q3, float b3v,
                                               float acc) {
    float t = __fadd_rn(__fmul_rn(q3, b3v), acc);
    t = __fadd_rn(__fmul_rn(q2, b2v), t);
    t = __fadd_rn(__fmul_rn(q1, b1v), t);
    return __fadd_rn(__fmul_rn(q0, b0v), t);
}

__device__ __forceinline__ float np_score(const float* __restrict__ qrow,
                                          const float* __restrict__ crow) {
    float acc0 = 0.f, acc1 = 0.f, acc2 = 0.f, acc3 = 0.f;
#pragma unroll
    for (int d0 = 0; d0 < D_DIM; d0 += 16) {
        float4 b0 = *reinterpret_cast<const float4*>(crow + d0 + 0);
        float4 b1 = *reinterpret_cast<const float4*>(crow + d0 + 4);
        float4 b2 = *reinterpret_cast<const float4*>(crow + d0 + 8);
        float4 b3 = *reinterpret_cast<const float4*>(crow + d0 + 12);
        acc0 = np_lane_chain(qrow[d0 + 0], b0.x, qrow[d0 + 4], b1.x,
                             qrow[d0 + 8], b2.x, qrow[d0 + 12], b3.x, acc0);
        acc1 = np_lane_chain(qrow[d0 + 1], b0.y, qrow[d0 + 5], b1.y,
                             qrow[d0 + 9], b2.y, qrow[d0 + 13], b3.y, acc1);
        acc2 = np_lane_chain(qrow[d0 + 2], b0.z, qrow[d0 + 6], b1.z,
                             qrow[d0 + 10], b2.z, qrow[d0 + 14], b3.z, acc2);
        acc3 = np_lane_chain(qrow[d0 + 3], b0.w, qrow[d0 + 7], b1.w,
                             qrow[d0 + 11], b2.w, qrow[d0 + 15], b3.w, acc3);
    }
    return __fadd_rn(__fadd_rn(acc0, acc1), __fadd_rn(acc2, acc3));
}

// selection: numpy-exact fp32 re-score, rank by (value desc, id asc)
__global__ __launch_bounds__(256) void select_kernel(
    const float* __restrict__ Qm, const float* __restrict__ cand,
    const unsigned* __restrict__ idbuf, const int* __restrict__ cnt,
    const int* __restrict__ ident, float* __restrict__ out, int N, int B, int cap) {
    __shared__ unsigned long long skey[CAP_MAX];
    __shared__ float qrow[D_DIM];
    int q = blockIdx.x;
    for (int i = threadIdx.x; i < D_DIM; i += blockDim.x) qrow[i] = Qm[(size_t)q * D_DIM + i];
    __syncthreads();

    int n = cnt[q]; if (n > cap) n = cap; if (n > CAP_MAX) n = CAP_MAX;
    for (int i = threadIdx.x; i < CAP_MAX; i += blockDim.x) {
        unsigned long long key = 0ULL;
        if (i < n) {
            unsigned id = idbuf[(size_t)q * cap + i];
            if (id < (unsigned)N) {
                float s = np_score(qrow, cand + (size_t)id * D_DIM);
                key = make_key(s, id);
            }
        }
        skey[i] = key;
    }

    bitonic_sort_u64<CAP_MAX>(skey);   // ascending: best at the end

    for (int t = threadIdx.x; t < K_TOP; t += blockDim.x) {
        unsigned long long key = skey[CAP_MAX - 1 - t];
        unsigned vm = (unsigned)(key >> 32);
        unsigned vb = (vm & 0x80000000u) ? (vm ^ 0x80000000u) : ~vm;
        unsigned id = 0xFFFFFFFFu - (unsigned)(key & 0xFFFFFFFFu);
        if (id >= (unsigned)N) id = 0;  // unreachable pad guard
        out[(size_t)q * K_TOP + t] = __uint_as_float(vb);
        out[(size_t)B * K_TOP + (size_t)q * K_TOP + t] = (float)ident[id];
    }
}

extern "C" void kernel_launch(void* const* d_in, const int* in_sizes, int n_in,
                              void* d_out, int out_size, void* d_ws, size_t ws_size,
                              hipStream_t stream) {
    const float* queries = (const float*)d_in[0];
    const float* cands   = (const float*)d_in[1];
    const int*   ident   = (const int*)d_in[2];
    const int B = in_sizes[0] / D_DIM;   // 512
    const int N = in_sizes[2];           // 500000
    float* out = (float*)d_out;
    const int nch = (B + 127) >> 7;
    const int ntiles = (N + TROWS - 1) / TROWS;

    // ws layout: cnt (2KB) | thr (2KB) | qfrag (nch*32KB) | idbuf
    char* ws = (char*)d_ws;
    int*   cnt = (int*)ws;
    float* thr = (float*)(ws + 2048);
    uint4* qfrag = (uint4*)(ws + 4096);
    size_t ids_off = 4096 + (size_t)nch * 32768;
    unsigned* idbuf = (unsigned*)(ws + ids_off);
    int cap = CAP_MAX;
    if (ws_size > ids_off) {
        size_t fit = (ws_size - ids_off) / ((size_t)B * 4);
        if (fit < (size_t)cap) cap = (int)fit;
    } else cap = 1;
    if (cap < 1) cap = 1;

    prep2_kernel<<<(B + 255) / 256, 256, 0, stream>>>(queries, thr, cnt, B);
    int qft = nch * 2048;
    qfrag_kernel<<<(qft + 255) / 256, 256, 0, stream>>>(queries, qfrag, B, nch);

    // filter per 512-query group (one group for B=512)
    int ngrp = (nch + 3) / 4;
    for (int g = 0; g < ngrp; ++g) {
        int nch_g = nch - g * 4; if (nch_g > 4) nch_g = 4;
        int B_g = B - g * 512; if (B_g > 512) B_g = 512;
        mfma_filter_kernel<<<FGRID, 256, 0, stream>>>(
            cands, (const bf16x8*)(qfrag + (size_t)g * 8192),
            thr + (size_t)g * 512, idbuf + (size_t)g * 512 * cap,
            cnt + (size_t)g * 512, N, B_g, cap, nch_g, ntiles);
    }

    fallback_kernel<<<B, 256, 0, stream>>>(queries, cands, idbuf, cnt, N, cap);

    select_kernel<<<B, 256, 0, stream>>>(queries, cands, idbuf, cnt, ident, out, N, B, cap);
}